// Round 15
// baseline (330.550 us; speedup 1.0000x reference)
//
#include <hip/hip_runtime.h>
#include <hip/hip_bf16.h>

#define AS1 __attribute__((address_space(1)))
#define AS3 __attribute__((address_space(3)))

typedef __hip_bfloat16 bf16;
typedef short bf16x8 __attribute__((ext_vector_type(8)));
typedef float f32x4 __attribute__((ext_vector_type(4)));

static constexpr int D = 1024, S = 2048, NB = 4, NH = 16, DK = 64;
static constexpr int M = NB * S;  // 8192

__device__ __forceinline__ void gload16(void* lds_dst, const void* gsrc) {
  __builtin_amdgcn_global_load_lds((const AS1 void*)gsrc, (AS3 void*)lds_dst, 16, 0, 0);
}

// ---------------- fp32 -> bf16 convert ----------------
__global__ void cvt_bf16_kernel(const float* __restrict__ src, bf16* __restrict__ dst, int n) {
  int i = (blockIdx.x * blockDim.x + threadIdx.x) * 4;
  int stride = gridDim.x * blockDim.x * 4;
  for (; i < n; i += stride) {
    float4 v = *(const float4*)(src + i);
    union { bf16 h[4]; uint2 u; } t;
    t.h[0] = __float2bfloat16(v.x);
    t.h[1] = __float2bfloat16(v.y);
    t.h[2] = __float2bfloat16(v.z);
    t.h[3] = __float2bfloat16(v.w);
    *(uint2*)(dst + i) = t.u;
  }
}

// ---------------- NT GEMM: C[m,n] = sum_k A[m,k]*Bw[n,k] ----------------
template <int MODE>
__global__ __launch_bounds__(256)
void gemm_bt(const bf16* __restrict__ A, const bf16* __restrict__ Bw,
             void* __restrict__ out, int K, int ldc, float scale) {
  __shared__ __align__(16) char lds[32768];
  char* Asm = lds;
  char* Bsm = lds + 16384;
  const int tid = threadIdx.x;
  const int w = tid >> 6, l = tid & 63;
  const int ql = l & 15, g = l >> 4;
  const int rowA = blockIdx.x * 128;
  const int rowB = blockIdx.y * 128;
  const int wr = (w >> 1) * 64, wc = (w & 1) * 64;

  f32x4 acc[4][4] = {};

  for (int k0 = 0; k0 < K; k0 += 64) {
#pragma unroll
    for (int i = 0; i < 4; ++i) {
      int o = ((i * 4 + w) << 10) + (l << 4);
      int row = o >> 7;
      int u = ((o >> 4) & 7) ^ (row & 7);
      gload16(Asm + ((i * 4 + w) << 10), A + (size_t)(rowA + row) * K + k0 + (u << 3));
      gload16(Bsm + ((i * 4 + w) << 10), Bw + (size_t)(rowB + row) * K + k0 + (u << 3));
    }
    __syncthreads();
#pragma unroll
    for (int kk = 0; kk < 2; ++kk) {
      bf16x8 af[4], bfr[4];
#pragma unroll
      for (int m = 0; m < 4; ++m) {
        int row = wr + m * 16 + ql;
        int sub = ((kk << 2) + g) ^ (row & 7);
        af[m] = *(const bf16x8*)(Asm + row * 128 + sub * 16);
      }
#pragma unroll
      for (int n = 0; n < 4; ++n) {
        int row = wc + n * 16 + ql;
        int sub = ((kk << 2) + g) ^ (row & 7);
        bfr[n] = *(const bf16x8*)(Bsm + row * 128 + sub * 16);
      }
#pragma unroll
      for (int m = 0; m < 4; ++m)
#pragma unroll
        for (int n = 0; n < 4; ++n)
          acc[m][n] = __builtin_amdgcn_mfma_f32_16x16x32_bf16(af[m], bfr[n], acc[m][n], 0, 0, 0);
    }
    __syncthreads();
  }

#pragma unroll
  for (int m = 0; m < 4; ++m)
#pragma unroll
    for (int n = 0; n < 4; ++n)
#pragma unroll
      for (int r = 0; r < 4; ++r) {
        int gm = rowA + wr + m * 16 + g * 4 + r;
        int gn = rowB + wc + n * 16 + ql;
        float v = acc[m][n][r] * scale;
        if (MODE == 0) {
          int b = gm >> 11, s = gm & 2047, h = gn >> 6, d = gn & 63;
          ((bf16*)out)[(((size_t)(b * 16 + h) * S) + s) * DK + d] = __float2bfloat16(v);
        } else if (MODE == 1) {
          int b = gn >> 11, s = gn & 2047;
          ((bf16*)out)[((size_t)b * 1024 + gm) * S + s] = __float2bfloat16(v);
        } else {
          ((float*)out)[(size_t)gm * ldc + gn] = v;
        }
      }
}

// ---------------- causal flash attention (v11: fixed-max + 4-wave split-KV sum-merge) ----------------
// 2048 blocks x 4 waves. id: bh=(id&7)+8*(id>>8) (32 blocks/head, XCD-local),
// pair pr=(id>>3)&31. Block handles strips {pr, 63-pr} (33 tiles total - uniform
// across ALL blocks). Per strip: wave w takes tiles t==w (mod 4); softmax uses a
// FIXED offset FM (no online max: scores log2-units, observed max ~12 << 135
// overflow bound) so partials merge by PURE SUM through LDS. Each wave then
// combines all 4 partials for its own 16-col block and writes O.
// 3 blocks/CU (51KB LDS) -> 3 waves/SIMD. Q pre-scaled by (1/8)*log2(e).
// Q,K: [B,H,S,64]; Vt: [B,H,64,S]; O: [B,S,H*64]
__global__ __launch_bounds__(256)
void attn_kernel(const bf16* __restrict__ Q, const bf16* __restrict__ Km,
                 const bf16* __restrict__ Vt, bf16* __restrict__ O) {
  __shared__ __align__(16) char P[4][2][2048];   // per-wave per-sub [16q][64kv] bf16, swizzled
  __shared__ float CB[4][64][35];                 // per-wave partials (stride 35: conflict-free)
  const int tid = threadIdx.x;
  const int w = tid >> 6, l = tid & 63;
  const int ql = l & 15, g = l >> 4;
  const int id = blockIdx.x;
  const int bh = (id & 7) + 8 * (id >> 8);   // XCD-local head
  const int pr = (id >> 3) & 31;             // pair index 0..31
  const int swz = (ql & 7) << 4;
  const float FM = 10.0f;                    // fixed softmax offset (log2 units)

  const bf16* Qb = Q + (size_t)bh * S * DK;
  const bf16* Kb = Km + (size_t)bh * S * DK;
  const bf16* Vb = Vt + (size_t)bh * DK * S;
  const int bo = bh >> 4, hh = bh & 15;
  bf16* Ob = O + (size_t)bo * S * D + hh * 64;

  for (int round = 0; round < 2; ++round) {
    const int j = round ? 63 - pr : pr;             // strip 0..63
    const int qbase = j << 5;                       // 32 q-rows
    const int kv_end = qbase + 32;
    const int T = (kv_end + 63) >> 6;               // kv tiles in this strip

    bf16x8 qf[2][2];
#pragma unroll
    for (int sub = 0; sub < 2; ++sub)
#pragma unroll
      for (int kk = 0; kk < 2; ++kk)
        qf[sub][kk] = *(const bf16x8*)(Qb + (size_t)(qbase + sub * 16 + ql) * DK + kk * 32 + g * 8);

    f32x4 oacc[2][4] = {};
    float lrow[2] = {0.f, 0.f};

    for (int t = w; t < T; t += 4) {
      const int kv0 = t << 6;
      const bool maskT = (t == T - 1);

      // ---- V loads first: fly during QK^T + softmax ----
      bf16x8 vf[2][4];
#pragma unroll
      for (int kk = 0; kk < 2; ++kk)
#pragma unroll
        for (int n = 0; n < 4; ++n)
          vf[kk][n] = *(const bf16x8*)(Vb + (size_t)(n * 16 + ql) * S + kv0 + kk * 32 + g * 8);

      // ---- QK^T (scores in log2 units via Q prescale) ----
      f32x4 st[2][4];
#pragma unroll
      for (int sub = 0; sub < 2; ++sub)
#pragma unroll
        for (int mt = 0; mt < 4; ++mt) st[sub][mt] = f32x4{0.f, 0.f, 0.f, 0.f};
      __builtin_amdgcn_s_setprio(1);
#pragma unroll
      for (int kk = 0; kk < 2; ++kk) {
        bf16x8 kf[4];
#pragma unroll
        for (int mt = 0; mt < 4; ++mt)
          kf[mt] = *(const bf16x8*)(Kb + (size_t)(kv0 + mt * 16 + ql) * DK + kk * 32 + g * 8);
#pragma unroll
        for (int sub = 0; sub < 2; ++sub)
#pragma unroll
          for (int mt = 0; mt < 4; ++mt)
            st[sub][mt] = __builtin_amdgcn_mfma_f32_16x16x32_bf16(kf[mt], qf[sub][kk], st[sub][mt], 0, 0, 0);
      }
      __builtin_amdgcn_s_setprio(0);

      // ---- softmax: fixed offset, no max tracking, no cross-lane ----
#pragma unroll
      for (int sub = 0; sub < 2; ++sub) {
        const int qpos = qbase + sub * 16 + ql;
        if (maskT) {
#pragma unroll
          for (int mt = 0; mt < 4; ++mt)
#pragma unroll
            for (int r = 0; r < 4; ++r) {
              int kvpos = kv0 + mt * 16 + g * 4 + r;
              if (kvpos > qpos) st[sub][mt][r] = -3e38f;
            }
        }
        float ps[4];
#pragma unroll
        for (int mt = 0; mt < 4; ++mt) {
          float e0 = exp2f(st[sub][mt][0] - FM);
          float e1 = exp2f(st[sub][mt][1] - FM);
          float e2 = exp2f(st[sub][mt][2] - FM);
          float e3 = exp2f(st[sub][mt][3] - FM);
          ps[mt] = (e0 + e1) + (e2 + e3);
          union { ushort us[4]; uint2 u; } pk;
          union { bf16 b; ushort u; } cv;
          cv.b = __float2bfloat16(e0); pk.us[0] = cv.u;
          cv.b = __float2bfloat16(e1); pk.us[1] = cv.u;
          cv.b = __float2bfloat16(e2); pk.us[2] = cv.u;
          cv.b = __float2bfloat16(e3); pk.us[3] = cv.u;
          *(uint2*)&P[w][sub][((ql << 7) + (mt << 5) + (g << 3)) ^ swz] = pk.u;
        }
        lrow[sub] += (ps[0] + ps[1]) + (ps[2] + ps[3]);
      }

      // ---- PV ----
      __builtin_amdgcn_s_setprio(1);
#pragma unroll
      for (int kk = 0; kk < 2; ++kk)
#pragma unroll
        for (int sub = 0; sub < 2; ++sub) {
          bf16x8 pa = *(const bf16x8*)&P[w][sub][((ql << 7) + (kk << 6) + (g << 4)) ^ swz];
#pragma unroll
          for (int n = 0; n < 4; ++n)
            oacc[sub][n] = __builtin_amdgcn_mfma_f32_16x16x32_bf16(pa, vf[kk][n], oacc[sub][n], 0, 0, 0);
        }
      __builtin_amdgcn_s_setprio(0);
    }

    // ---- merge: pure sum of 4 waves' partials (fixed offset -> no exp weights) ----
    {
      float* cb = &CB[w][l][0];
#pragma unroll
      for (int sub = 0; sub < 2; ++sub)
#pragma unroll
        for (int n = 0; n < 4; ++n)
#pragma unroll
          for (int r = 0; r < 4; ++r)
            cb[sub * 16 + n * 4 + r] = oacc[sub][n][r];
      cb[32] = lrow[0];
      cb[33] = lrow[1];
    }
    __syncthreads();
    // each wave combines + writes its own 16-col block (n = w)
#pragma unroll
    for (int sub = 0; sub < 2; ++sub) {
      float lr = CB[0][l][32 + sub] + CB[1][l][32 + sub] + CB[2][l][32 + sub] + CB[3][l][32 + sub];
      lr += __shfl_xor(lr, 16, 64);
      lr += __shfl_xor(lr, 32, 64);
      float of[4];
#pragma unroll
      for (int r = 0; r < 4; ++r) {
        int idx = sub * 16 + w * 4 + r;
        of[r] = CB[0][l][idx] + CB[1][l][idx] + CB[2][l][idx] + CB[3][l][idx];
      }
      float ldv[4];
#pragma unroll
      for (int r = 0; r < 4; ++r) ldv[r] = __shfl(lr, g * 4 + r, 16);
#pragma unroll
      for (int r = 0; r < 4; ++r) {
        int qrow = qbase + sub * 16 + g * 4 + r;
        Ob[(size_t)qrow * D + w * 16 + ql] = __float2bfloat16(of[r] / ldv[r]);
      }
    }
    __syncthreads();   // CB reused next round
  }
}

extern "C" void kernel_launch(void* const* d_in, const int* in_sizes, int n_in,
                              void* d_out, int out_size, void* d_ws, size_t ws_size,
                              hipStream_t stream) {
  const float* x  = (const float*)d_in[0];
  const float* wq = (const float*)d_in[1];
  const float* wk = (const float*)d_in[2];
  const float* wv = (const float*)d_in[3];
  const float* wo = (const float*)d_in[4];

  char* ws = (char*)d_ws;
  bf16* xb  = (bf16*)(ws);                      // 16 MB  [8192,1024]
  bf16* wqb = (bf16*)(ws + (16u << 20));        // 2 MB
  bf16* wkb = (bf16*)(ws + (18u << 20));
  bf16* wvb = (bf16*)(ws + (20u << 20));
  bf16* wob = (bf16*)(ws + (22u << 20));
  bf16* Qb  = (bf16*)(ws + (24u << 20));        // 16 MB [B,H,S,64] (pre-scaled, log2 units)
  bf16* Kb  = (bf16*)(ws + (40u << 20));        // 16 MB [B,H,S,64]
  bf16* Vtb = (bf16*)(ws + (56u << 20));        // 16 MB [B,H,64,S]
  bf16* Ob  = (bf16*)(ws + (72u << 20));        // 16 MB [8192,1024]

  cvt_bf16_kernel<<<2048, 256, 0, stream>>>(x, xb, M * D);
  cvt_bf16_kernel<<<1024, 256, 0, stream>>>(wq, wqb, D * D);
  cvt_bf16_kernel<<<1024, 256, 0, stream>>>(wk, wkb, D * D);
  cvt_bf16_kernel<<<1024, 256, 0, stream>>>(wv, wvb, D * D);
  cvt_bf16_kernel<<<1024, 256, 0, stream>>>(wo, wob, D * D);

  // Q = x Wq^T scaled by (1/8)*log2(e)  -> scores come out in log2 units
  gemm_bt<0><<<dim3(M / 128, D / 128), 256, 0, stream>>>(xb, wqb, Qb, D, D, 0.18033688f);
  gemm_bt<0><<<dim3(M / 128, D / 128), 256, 0, stream>>>(xb, wkb, Kb, D, D, 1.0f);
  // Vt = Wv x^T -> [B,H,64,S]
  gemm_bt<1><<<dim3(D / 128, M / 128), 256, 0, stream>>>(wvb, xb, Vtb, D, D, 1.0f);

  attn_kernel<<<dim3(2048), 256, 0, stream>>>(Qb, Kb, Vtb, Ob);

  // out = O Wo^T (fp32)
  gemm_bt<2><<<dim3(M / 128, D / 128), 256, 0, stream>>>(Ob, wob, d_out, D, D, 1.0f);
}

// Round 18
// 265.690 us; speedup vs baseline: 1.2441x; 1.2441x over previous
//
#include <hip/hip_runtime.h>
#include <hip/hip_bf16.h>

#define AS1 __attribute__((address_space(1)))
#define AS3 __attribute__((address_space(3)))

typedef __hip_bfloat16 bf16;
typedef short bf16x8 __attribute__((ext_vector_type(8)));
typedef float f32x4 __attribute__((ext_vector_type(4)));

static constexpr int D = 1024, S = 2048, NB = 4, NH = 16, DK = 64;
static constexpr int M = NB * S;  // 8192

__device__ __forceinline__ void gload16(void* lds_dst, const void* gsrc) {
  __builtin_amdgcn_global_load_lds((const AS1 void*)gsrc, (AS3 void*)lds_dst, 16, 0, 0);
}

// ---------------- fp32 -> bf16 convert ----------------
__global__ void cvt_bf16_kernel(const float* __restrict__ src, bf16* __restrict__ dst, int n) {
  int i = (blockIdx.x * blockDim.x + threadIdx.x) * 4;
  int stride = gridDim.x * blockDim.x * 4;
  for (; i < n; i += stride) {
    float4 v = *(const float4*)(src + i);
    union { bf16 h[4]; uint2 u; } t;
    t.h[0] = __float2bfloat16(v.x);
    t.h[1] = __float2bfloat16(v.y);
    t.h[2] = __float2bfloat16(v.z);
    t.h[3] = __float2bfloat16(v.w);
    *(uint2*)(dst + i) = t.u;
  }
}

// ---------------- NT GEMM: C[m,n] = sum_k A[m,k]*Bw[n,k] ----------------
template <int MODE>
__global__ __launch_bounds__(256)
void gemm_bt(const bf16* __restrict__ A, const bf16* __restrict__ Bw,
             void* __restrict__ out, int K, int ldc, float scale) {
  __shared__ __align__(16) char lds[32768];
  char* Asm = lds;
  char* Bsm = lds + 16384;
  const int tid = threadIdx.x;
  const int w = tid >> 6, l = tid & 63;
  const int ql = l & 15, g = l >> 4;
  const int rowA = blockIdx.x * 128;
  const int rowB = blockIdx.y * 128;
  const int wr = (w >> 1) * 64, wc = (w & 1) * 64;

  f32x4 acc[4][4] = {};

  for (int k0 = 0; k0 < K; k0 += 64) {
#pragma unroll
    for (int i = 0; i < 4; ++i) {
      int o = ((i * 4 + w) << 10) + (l << 4);
      int row = o >> 7;
      int u = ((o >> 4) & 7) ^ (row & 7);
      gload16(Asm + ((i * 4 + w) << 10), A + (size_t)(rowA + row) * K + k0 + (u << 3));
      gload16(Bsm + ((i * 4 + w) << 10), Bw + (size_t)(rowB + row) * K + k0 + (u << 3));
    }
    __syncthreads();
#pragma unroll
    for (int kk = 0; kk < 2; ++kk) {
      bf16x8 af[4], bfr[4];
#pragma unroll
      for (int m = 0; m < 4; ++m) {
        int row = wr + m * 16 + ql;
        int sub = ((kk << 2) + g) ^ (row & 7);
        af[m] = *(const bf16x8*)(Asm + row * 128 + sub * 16);
      }
#pragma unroll
      for (int n = 0; n < 4; ++n) {
        int row = wc + n * 16 + ql;
        int sub = ((kk << 2) + g) ^ (row & 7);
        bfr[n] = *(const bf16x8*)(Bsm + row * 128 + sub * 16);
      }
#pragma unroll
      for (int m = 0; m < 4; ++m)
#pragma unroll
        for (int n = 0; n < 4; ++n)
          acc[m][n] = __builtin_amdgcn_mfma_f32_16x16x32_bf16(af[m], bfr[n], acc[m][n], 0, 0, 0);
    }
    __syncthreads();
  }

#pragma unroll
  for (int m = 0; m < 4; ++m)
#pragma unroll
    for (int n = 0; n < 4; ++n)
#pragma unroll
      for (int r = 0; r < 4; ++r) {
        int gm = rowA + wr + m * 16 + g * 4 + r;
        int gn = rowB + wc + n * 16 + ql;
        float v = acc[m][n][r] * scale;
        if (MODE == 0) {
          int b = gm >> 11, s = gm & 2047, h = gn >> 6, d = gn & 63;
          ((bf16*)out)[(((size_t)(b * 16 + h) * S) + s) * DK + d] = __float2bfloat16(v);
        } else if (MODE == 1) {
          int b = gn >> 11, s = gn & 2047;
          ((bf16*)out)[((size_t)b * 1024 + gm) * S + s] = __float2bfloat16(v);
        } else {
          ((float*)out)[(size_t)gm * ldc + gn] = v;
        }
      }
}

// ---------------- causal flash attention (v12: v7 + in-wave 2-stream split-KV) ----------------
// 512 blocks x 4 waves. id: head bh=(id&7)+8*(id>>6) (8 blocks/head, XCD-local),
// x=(id>>3)&7. Wave w owns pair p = x + 8w, processes strips {p, 63-p}
// sequentially (65 tiles/wave - uniform). NEW: within each strip, kv tiles are
// split into two EQUAL independent streams A=[0,nP) and B=[nP,2nP) interleaved
// in program order (leftover odd tile solo) -> compiler interleaves the two
// dependency chains, filling v7's ~45% no-issue. Streams merge IN-REGISTER
// (exact split-softmax combine; no LDS merge, no barrier).
// Q pre-scaled by (1/8)*log2(e): exp2-direct softmax.
// Q,K: [B,H,S,64]; Vt: [B,H,64,S]; O: [B,S,H*64]
struct SM2 {
  f32x4 oacc[2][4];
  float mrow[2];
  float lrow[2];
};

__device__ __forceinline__ void attn_tile(
    const bf16* __restrict__ Kb, const bf16* __restrict__ Vb, char* Pst,
    const bf16x8 (&qf)[2][2], SM2& s, int kv0, int qbase, bool last,
    int ql, int g, int swz) {
  // ---- QK^T (scores in log2 units via Q prescale) ----
  f32x4 st[2][4];
#pragma unroll
  for (int sub = 0; sub < 2; ++sub)
#pragma unroll
    for (int mt = 0; mt < 4; ++mt) st[sub][mt] = f32x4{0.f, 0.f, 0.f, 0.f};
  __builtin_amdgcn_s_setprio(1);
#pragma unroll
  for (int kk = 0; kk < 2; ++kk) {
    bf16x8 kf[4];
#pragma unroll
    for (int mt = 0; mt < 4; ++mt)
      kf[mt] = *(const bf16x8*)(Kb + (size_t)(kv0 + mt * 16 + ql) * DK + kk * 32 + g * 8);
#pragma unroll
    for (int sub = 0; sub < 2; ++sub)
#pragma unroll
      for (int mt = 0; mt < 4; ++mt)
        st[sub][mt] = __builtin_amdgcn_mfma_f32_16x16x32_bf16(kf[mt], qf[sub][kk], st[sub][mt], 0, 0, 0);
  }
  __builtin_amdgcn_s_setprio(0);

  // ---- softmax (defer-max, lane-local common path, exp2-direct) ----
#pragma unroll
  for (int sub = 0; sub < 2; ++sub) {
    const int qpos = qbase + sub * 16 + ql;
    if (last) {
#pragma unroll
      for (int mt = 0; mt < 4; ++mt)
#pragma unroll
        for (int r = 0; r < 4; ++r) {
          int kvpos = kv0 + mt * 16 + g * 4 + r;
          if (kvpos > qpos) st[sub][mt][r] = -3e38f;
        }
    }
    float tm[4];
#pragma unroll
    for (int mt = 0; mt < 4; ++mt)
      tm[mt] = fmaxf(fmaxf(st[sub][mt][0], st[sub][mt][1]),
                     fmaxf(st[sub][mt][2], st[sub][mt][3]));
    float tmax = fmaxf(fmaxf(tm[0], tm[1]), fmaxf(tm[2], tm[3]));
    if (__any(tmax > s.mrow[sub] + 8.0f)) {
      float rm = tmax;
      rm = fmaxf(rm, __shfl_xor(rm, 16, 64));
      rm = fmaxf(rm, __shfl_xor(rm, 32, 64));
      float mnew = fmaxf(s.mrow[sub], rm);
      float sc = exp2f(s.mrow[sub] - mnew);
      s.mrow[sub] = mnew;
      s.lrow[sub] *= sc;
#pragma unroll
      for (int r = 0; r < 4; ++r) {             // acc rows are q = g*4+r
        float scr = __shfl(sc, g * 4 + r, 16);
#pragma unroll
        for (int n = 0; n < 4; ++n) s.oacc[sub][n][r] *= scr;
      }
    }
    float ps[4];
#pragma unroll
    for (int mt = 0; mt < 4; ++mt) {
      float e0 = exp2f(st[sub][mt][0] - s.mrow[sub]);
      float e1 = exp2f(st[sub][mt][1] - s.mrow[sub]);
      float e2 = exp2f(st[sub][mt][2] - s.mrow[sub]);
      float e3 = exp2f(st[sub][mt][3] - s.mrow[sub]);
      ps[mt] = (e0 + e1) + (e2 + e3);
      union { ushort us[4]; uint2 u; } pk;
      union { bf16 b; ushort u; } cv;
      cv.b = __float2bfloat16(e0); pk.us[0] = cv.u;
      cv.b = __float2bfloat16(e1); pk.us[1] = cv.u;
      cv.b = __float2bfloat16(e2); pk.us[2] = cv.u;
      cv.b = __float2bfloat16(e3); pk.us[3] = cv.u;
      *(uint2*)&Pst[(size_t)sub * 2048 + (((ql << 7) + (mt << 5) + (g << 3)) ^ swz)] = pk.u;
    }
    s.lrow[sub] += (ps[0] + ps[1]) + (ps[2] + ps[3]);
  }

  // ---- V loads just before PV (other stream covers the latency) ----
  bf16x8 vf[2][4];
#pragma unroll
  for (int kk = 0; kk < 2; ++kk)
#pragma unroll
    for (int n = 0; n < 4; ++n)
      vf[kk][n] = *(const bf16x8*)(Vb + (size_t)(n * 16 + ql) * S + kv0 + kk * 32 + g * 8);

  // ---- PV ----
  __builtin_amdgcn_s_setprio(1);
#pragma unroll
  for (int kk = 0; kk < 2; ++kk)
#pragma unroll
    for (int sub = 0; sub < 2; ++sub) {
      bf16x8 pa = *(const bf16x8*)&Pst[(size_t)sub * 2048 + (((ql << 7) + (kk << 6) + (g << 4)) ^ swz)];
#pragma unroll
      for (int n = 0; n < 4; ++n)
        s.oacc[sub][n] = __builtin_amdgcn_mfma_f32_16x16x32_bf16(pa, vf[kk][n], s.oacc[sub][n], 0, 0, 0);
    }
  __builtin_amdgcn_s_setprio(0);
}

__global__ __launch_bounds__(256)
void attn_kernel(const bf16* __restrict__ Q, const bf16* __restrict__ Km,
                 const bf16* __restrict__ Vt, bf16* __restrict__ O) {
  __shared__ __align__(16) char P[4][2][2][2048];  // [wave][stream][sub][16q x 64kv bf16]
  const int tid = threadIdx.x;
  const int w = tid >> 6, l = tid & 63;
  const int ql = l & 15, g = l >> 4;
  const int id = blockIdx.x;
  const int bh = (id & 7) + 8 * (id >> 6);   // XCD-local head
  const int x = (id >> 3) & 7;
  const int p = x + 8 * w;                   // pair index 0..31
  const int swz = (ql & 7) << 4;

  const bf16* Qb = Q + (size_t)bh * S * DK;
  const bf16* Kb = Km + (size_t)bh * S * DK;
  const bf16* Vb = Vt + (size_t)bh * DK * S;
  const int bo = bh >> 4, hh = bh & 15;
  bf16* Ob = O + (size_t)bo * S * D + hh * 64;

  for (int round = 0; round < 2; ++round) {
    const int j = round ? 63 - p : p;               // strip 0..63
    const int qbase = j << 5;                       // 32 q-rows
    const int kv_end = qbase + 32;
    const int T = (kv_end + 63) >> 6;               // kv tiles in strip
    const int nP = T >> 1;

    bf16x8 qf[2][2];
#pragma unroll
    for (int sub = 0; sub < 2; ++sub)
#pragma unroll
      for (int kk = 0; kk < 2; ++kk)
        qf[sub][kk] = *(const bf16x8*)(Qb + (size_t)(qbase + sub * 16 + ql) * DK + kk * 32 + g * 8);

    SM2 sA = {}, sB = {};
    sA.mrow[0] = sA.mrow[1] = -3e38f;
    sB.mrow[0] = sB.mrow[1] = -3e38f;
    char* PA = &P[w][0][0][0];
    char* PB = &P[w][1][0][0];

    // interleaved equal streams: A = tiles [0,nP), B = tiles [nP,2nP)
    for (int i = 0; i < nP; ++i) {
      attn_tile(Kb, Vb, PA, qf, sA, i << 6, qbase, false, ql, g, swz);
      attn_tile(Kb, Vb, PB, qf, sB, (nP + i) << 6, qbase, (nP + i) == T - 1, ql, g, swz);
    }
    if (T & 1)  // leftover tile = T-1 (the masked one), solo on stream A
      attn_tile(Kb, Vb, PA, qf, sA, (T - 1) << 6, qbase, true, ql, g, swz);

    // ---- in-register split-softmax merge + epilogue ----
#pragma unroll
    for (int sub = 0; sub < 2; ++sub) {
      float m = fmaxf(sA.mrow[sub], sB.mrow[sub]);
      float fA = exp2f(sA.mrow[sub] - m);
      float fB = exp2f(sB.mrow[sub] - m);
      float lr = fA * sA.lrow[sub] + fB * sB.lrow[sub];
      lr += __shfl_xor(lr, 16, 64);
      lr += __shfl_xor(lr, 32, 64);
      float ldv[4], fAr[4], fBr[4];
#pragma unroll
      for (int r = 0; r < 4; ++r) {
        ldv[r] = __shfl(lr, g * 4 + r, 16);
        fAr[r] = __shfl(fA, g * 4 + r, 16);
        fBr[r] = __shfl(fB, g * 4 + r, 16);
      }
#pragma unroll
      for (int r = 0; r < 4; ++r) {
        int qrow = qbase + sub * 16 + g * 4 + r;
        float inv = 1.f / ldv[r];
#pragma unroll
        for (int n = 0; n < 4; ++n) {
          float ov = fAr[r] * sA.oacc[sub][n][r] + fBr[r] * sB.oacc[sub][n][r];
          Ob[(size_t)qrow * D + n * 16 + ql] = __float2bfloat16(ov * inv);
        }
      }
    }
  }
}

extern "C" void kernel_launch(void* const* d_in, const int* in_sizes, int n_in,
                              void* d_out, int out_size, void* d_ws, size_t ws_size,
                              hipStream_t stream) {
  const float* x  = (const float*)d_in[0];
  const float* wq = (const float*)d_in[1];
  const float* wk = (const float*)d_in[2];
  const float* wv = (const float*)d_in[3];
  const float* wo = (const float*)d_in[4];

  char* ws = (char*)d_ws;
  bf16* xb  = (bf16*)(ws);                      // 16 MB  [8192,1024]
  bf16* wqb = (bf16*)(ws + (16u << 20));        // 2 MB
  bf16* wkb = (bf16*)(ws + (18u << 20));
  bf16* wvb = (bf16*)(ws + (20u << 20));
  bf16* wob = (bf16*)(ws + (22u << 20));
  bf16* Qb  = (bf16*)(ws + (24u << 20));        // 16 MB [B,H,S,64] (pre-scaled, log2 units)
  bf16* Kb  = (bf16*)(ws + (40u << 20));        // 16 MB [B,H,S,64]
  bf16* Vtb = (bf16*)(ws + (56u << 20));        // 16 MB [B,H,64,S]
  bf16* Ob  = (bf16*)(ws + (72u << 20));        // 16 MB [8192,1024]

  cvt_bf16_kernel<<<2048, 256, 0, stream>>>(x, xb, M * D);
  cvt_bf16_kernel<<<1024, 256, 0, stream>>>(wq, wqb, D * D);
  cvt_bf16_kernel<<<1024, 256, 0, stream>>>(wk, wkb, D * D);
  cvt_bf16_kernel<<<1024, 256, 0, stream>>>(wv, wvb, D * D);
  cvt_bf16_kernel<<<1024, 256, 0, stream>>>(wo, wob, D * D);

  // Q = x Wq^T scaled by (1/8)*log2(e)  -> scores come out in log2 units
  gemm_bt<0><<<dim3(M / 128, D / 128), 256, 0, stream>>>(xb, wqb, Qb, D, D, 0.18033688f);
  gemm_bt<0><<<dim3(M / 128, D / 128), 256, 0, stream>>>(xb, wkb, Kb, D, D, 1.0f);
  // Vt = Wv x^T -> [B,H,64,S]
  gemm_bt<1><<<dim3(D / 128, M / 128), 256, 0, stream>>>(wvb, xb, Vtb, D, D, 1.0f);

  attn_kernel<<<dim3(512), 256, 0, stream>>>(Qb, Kb, Vtb, Ob);

  // out = O Wo^T (fp32)
  gemm_bt<2><<<dim3(M / 128, D / 128), 256, 0, stream>>>(Ob, wob, d_out, D, D, 1.0f);
}

// Round 21
// 233.102 us; speedup vs baseline: 1.4180x; 1.1398x over previous
//
#include <hip/hip_runtime.h>
#include <hip/hip_bf16.h>

#define AS1 __attribute__((address_space(1)))
#define AS3 __attribute__((address_space(3)))

typedef __hip_bfloat16 bf16;
typedef short bf16x8 __attribute__((ext_vector_type(8)));
typedef float f32x4 __attribute__((ext_vector_type(4)));

static constexpr int D = 1024, S = 2048, NB = 4, NH = 16, DK = 64;
static constexpr int M = NB * S;  // 8192

__device__ __forceinline__ void gload16(void* lds_dst, const void* gsrc) {
  __builtin_amdgcn_global_load_lds((const AS1 void*)gsrc, (AS3 void*)lds_dst, 16, 0, 0);
}

// ---------------- fp32 -> bf16 convert (x) ----------------
__global__ void cvt_bf16_kernel(const float* __restrict__ src, bf16* __restrict__ dst, int n) {
  int i = (blockIdx.x * blockDim.x + threadIdx.x) * 4;
  int stride = gridDim.x * blockDim.x * 4;
  for (; i < n; i += stride) {
    float4 v = *(const float4*)(src + i);
    union { bf16 h[4]; uint2 u; } t;
    t.h[0] = __float2bfloat16(v.x);
    t.h[1] = __float2bfloat16(v.y);
    t.h[2] = __float2bfloat16(v.z);
    t.h[3] = __float2bfloat16(v.w);
    *(uint2*)(dst + i) = t.u;
  }
}

// ---------------- fused fp32 -> bf16 convert for the 4 weights ----------------
__global__ void cvt_w4_kernel(const float* __restrict__ s0, const float* __restrict__ s1,
                              const float* __restrict__ s2, const float* __restrict__ s3,
                              bf16* __restrict__ d0, bf16* __restrict__ d1,
                              bf16* __restrict__ d2, bf16* __restrict__ d3) {
  const float* src;
  bf16* dst;
  if (blockIdx.y == 0)      { src = s0; dst = d0; }
  else if (blockIdx.y == 1) { src = s1; dst = d1; }
  else if (blockIdx.y == 2) { src = s2; dst = d2; }
  else                      { src = s3; dst = d3; }
  const int n = D * D;
  int i = (blockIdx.x * blockDim.x + threadIdx.x) * 4;
  int stride = gridDim.x * blockDim.x * 4;
  for (; i < n; i += stride) {
    float4 v = *(const float4*)(src + i);
    union { bf16 h[4]; uint2 u; } t;
    t.h[0] = __float2bfloat16(v.x);
    t.h[1] = __float2bfloat16(v.y);
    t.h[2] = __float2bfloat16(v.z);
    t.h[3] = __float2bfloat16(v.w);
    *(uint2*)(dst + i) = t.u;
  }
}

// ---------------- NT GEMM: C[m,n] = sum_k A[m,k]*Bw[n,k] ----------------
// MODE 0: write bf16 to [B,H,S,64] layout (proj for Q/K), scaled
// MODE 1: write bf16 to Vt [B,H,64,S] layout (A=Wv, B=x)
// MODE 2: write fp32 row-major [M,N] (final output projection)
template <int MODE>
__global__ __launch_bounds__(256)
void gemm_bt(const bf16* __restrict__ A, const bf16* __restrict__ Bw,
             void* __restrict__ out, int K, int ldc, float scale) {
  __shared__ __align__(16) char lds[32768];
  char* Asm = lds;
  char* Bsm = lds + 16384;
  const int tid = threadIdx.x;
  const int w = tid >> 6, l = tid & 63;
  const int ql = l & 15, g = l >> 4;
  const int rowA = blockIdx.x * 128;
  const int rowB = blockIdx.y * 128;
  const int wr = (w >> 1) * 64, wc = (w & 1) * 64;

  f32x4 acc[4][4] = {};

  for (int k0 = 0; k0 < K; k0 += 64) {
#pragma unroll
    for (int i = 0; i < 4; ++i) {
      int o = ((i * 4 + w) << 10) + (l << 4);
      int row = o >> 7;
      int u = ((o >> 4) & 7) ^ (row & 7);
      gload16(Asm + ((i * 4 + w) << 10), A + (size_t)(rowA + row) * K + k0 + (u << 3));
      gload16(Bsm + ((i * 4 + w) << 10), Bw + (size_t)(rowB + row) * K + k0 + (u << 3));
    }
    __syncthreads();
#pragma unroll
    for (int kk = 0; kk < 2; ++kk) {
      bf16x8 af[4], bfr[4];
#pragma unroll
      for (int m = 0; m < 4; ++m) {
        int row = wr + m * 16 + ql;
        int sub = ((kk << 2) + g) ^ (row & 7);
        af[m] = *(const bf16x8*)(Asm + row * 128 + sub * 16);
      }
#pragma unroll
      for (int n = 0; n < 4; ++n) {
        int row = wc + n * 16 + ql;
        int sub = ((kk << 2) + g) ^ (row & 7);
        bfr[n] = *(const bf16x8*)(Bsm + row * 128 + sub * 16);
      }
#pragma unroll
      for (int m = 0; m < 4; ++m)
#pragma unroll
        for (int n = 0; n < 4; ++n)
          acc[m][n] = __builtin_amdgcn_mfma_f32_16x16x32_bf16(af[m], bfr[n], acc[m][n], 0, 0, 0);
    }
    __syncthreads();
  }

#pragma unroll
  for (int m = 0; m < 4; ++m)
#pragma unroll
    for (int n = 0; n < 4; ++n)
#pragma unroll
      for (int r = 0; r < 4; ++r) {
        int gm = rowA + wr + m * 16 + g * 4 + r;
        int gn = rowB + wc + n * 16 + ql;
        float v = acc[m][n][r] * scale;
        if (MODE == 0) {
          int b = gm >> 11, s = gm & 2047, h = gn >> 6, d = gn & 63;
          ((bf16*)out)[(((size_t)(b * 16 + h) * S) + s) * DK + d] = __float2bfloat16(v);
        } else if (MODE == 1) {
          int b = gn >> 11, s = gn & 2047;
          ((bf16*)out)[((size_t)b * 1024 + gm) * S + s] = __float2bfloat16(v);
        } else {
          ((float*)out)[(size_t)gm * ldc + gn] = v;
        }
      }
}

// ---------------- causal flash attention (v7: complementary pairs in-wave) ----------------
// 512 blocks x 4 waves. id: head bh=(id&7)+8*(id>>6) (8 blocks/head, XCD-local),
// x=(id>>3)&7. Per head: 64 strips of 32 q-rows = 32 complementary pairs.
// Wave w owns pair p = x + 8w and processes strips {p, 63-p} sequentially
// -> exactly 65 kv-tiles for EVERY wave (perfect balance, no sync, no merge).
// KVBLK=64, per-sub P tiles, defer-max, V-hoist, setprio. Q pre-scaled by 1/8.
// Q,K: [B,H,S,64]; Vt: [B,H,64,S]; O: [B,S,H*64]
__global__ __launch_bounds__(256)
void attn_kernel(const bf16* __restrict__ Q, const bf16* __restrict__ Km,
                 const bf16* __restrict__ Vt, bf16* __restrict__ O) {
  __shared__ __align__(16) char P[4][2][2048];   // per-wave per-sub [16q][64kv] bf16, swizzled
  const int tid = threadIdx.x;
  const int w = tid >> 6, l = tid & 63;
  const int ql = l & 15, g = l >> 4;
  const int id = blockIdx.x;
  const int bh = (id & 7) + 8 * (id >> 6);   // XCD-local head
  const int x = (id >> 3) & 7;
  const int p = x + 8 * w;                   // pair index 0..31
  const int swz = (ql & 7) << 4;
  const float L2E = 1.44269504f;
  const float THR = 8.0f;

  const bf16* Qb = Q + (size_t)bh * S * DK;
  const bf16* Kb = Km + (size_t)bh * S * DK;
  const bf16* Vb = Vt + (size_t)bh * DK * S;
  const int bo = bh >> 4, hh = bh & 15;
  bf16* Ob = O + (size_t)bo * S * D + hh * 64;

  for (int round = 0; round < 2; ++round) {
    const int j = round ? 63 - p : p;               // strip 0..63
    const int qbase = j << 5;                       // 32 q-rows
    const int kv_end = qbase + 32;

    bf16x8 qf[2][2];
#pragma unroll
    for (int sub = 0; sub < 2; ++sub)
#pragma unroll
      for (int kk = 0; kk < 2; ++kk)
        qf[sub][kk] = *(const bf16x8*)(Qb + (size_t)(qbase + sub * 16 + ql) * DK + kk * 32 + g * 8);

    f32x4 oacc[2][4] = {};
    float mrow[2] = {-3e38f, -3e38f};
    float lrow[2] = {0.f, 0.f};

    for (int kv0 = 0; kv0 < kv_end; kv0 += 64) {
      const bool last = (kv0 + 64 >= kv_end);

      // ---- QK^T ----
      f32x4 st[2][4];
#pragma unroll
      for (int sub = 0; sub < 2; ++sub)
#pragma unroll
        for (int mt = 0; mt < 4; ++mt) st[sub][mt] = f32x4{0.f, 0.f, 0.f, 0.f};
      __builtin_amdgcn_s_setprio(1);
#pragma unroll
      for (int kk = 0; kk < 2; ++kk) {
        bf16x8 kf[4];
#pragma unroll
        for (int mt = 0; mt < 4; ++mt)
          kf[mt] = *(const bf16x8*)(Kb + (size_t)(kv0 + mt * 16 + ql) * DK + kk * 32 + g * 8);
#pragma unroll
        for (int sub = 0; sub < 2; ++sub)
#pragma unroll
          for (int mt = 0; mt < 4; ++mt)
            st[sub][mt] = __builtin_amdgcn_mfma_f32_16x16x32_bf16(kf[mt], qf[sub][kk], st[sub][mt], 0, 0, 0);
      }
      __builtin_amdgcn_s_setprio(0);

      // ---- hoist V loads (latency hides under softmax) ----
      bf16x8 vf[2][4];
#pragma unroll
      for (int kk = 0; kk < 2; ++kk)
#pragma unroll
        for (int n = 0; n < 4; ++n)
          vf[kk][n] = *(const bf16x8*)(Vb + (size_t)(n * 16 + ql) * S + kv0 + kk * 32 + g * 8);

      // ---- softmax (defer-max, lane-local common path) ----
#pragma unroll
      for (int sub = 0; sub < 2; ++sub) {
        const int qpos = qbase + sub * 16 + ql;
        if (last) {
#pragma unroll
          for (int mt = 0; mt < 4; ++mt)
#pragma unroll
            for (int r = 0; r < 4; ++r) {
              int kvpos = kv0 + mt * 16 + g * 4 + r;
              if (kvpos > qpos) st[sub][mt][r] = -3e38f;
            }
        }
        float tmax = st[sub][0][0];
#pragma unroll
        for (int mt = 0; mt < 4; ++mt)
#pragma unroll
          for (int r = 0; r < 4; ++r) tmax = fmaxf(tmax, st[sub][mt][r]);
        if (__any(tmax > mrow[sub] + THR)) {
          float rm = tmax;
          rm = fmaxf(rm, __shfl_xor(rm, 16, 64));
          rm = fmaxf(rm, __shfl_xor(rm, 32, 64));
          float mnew = fmaxf(mrow[sub], rm);
          float sc = exp2f((mrow[sub] - mnew) * L2E);
          mrow[sub] = mnew;
          lrow[sub] *= sc;
#pragma unroll
          for (int r = 0; r < 4; ++r) {            // acc rows are q = g*4+r
            float scr = __shfl(sc, g * 4 + r, 16);
#pragma unroll
            for (int n = 0; n < 4; ++n) oacc[sub][n][r] *= scr;
          }
        }
        float psum = 0.f;
#pragma unroll
        for (int mt = 0; mt < 4; ++mt) {
          union { ushort us[4]; uint2 u; } pk;
#pragma unroll
          for (int r = 0; r < 4; ++r) {
            float pv = exp2f((st[sub][mt][r] - mrow[sub]) * L2E);  // bounded by e^THR
            psum += pv;
            union { bf16 b; ushort u; } cv;
            cv.b = __float2bfloat16(pv);
            pk.us[r] = cv.u;
          }
          *(uint2*)&P[w][sub][((ql << 7) + (mt << 5) + (g << 3)) ^ swz] = pk.u;
        }
        lrow[sub] += psum;   // per-lane partial; reduced once in epilogue
      }

      // ---- PV ----
      __builtin_amdgcn_s_setprio(1);
#pragma unroll
      for (int kk = 0; kk < 2; ++kk)
#pragma unroll
        for (int sub = 0; sub < 2; ++sub) {
          bf16x8 pa = *(const bf16x8*)&P[w][sub][((ql << 7) + (kk << 6) + (g << 4)) ^ swz];
#pragma unroll
          for (int n = 0; n < 4; ++n)
            oacc[sub][n] = __builtin_amdgcn_mfma_f32_16x16x32_bf16(pa, vf[kk][n], oacc[sub][n], 0, 0, 0);
        }
      __builtin_amdgcn_s_setprio(0);
    }

    // ---- epilogue for this strip ----
#pragma unroll
    for (int sub = 0; sub < 2; ++sub) {
      float lr = lrow[sub];
      lr += __shfl_xor(lr, 16, 64);
      lr += __shfl_xor(lr, 32, 64);
      float ldv[4];
#pragma unroll
      for (int r = 0; r < 4; ++r) ldv[r] = __shfl(lr, g * 4 + r, 16);
#pragma unroll
      for (int r = 0; r < 4; ++r) {
        int qrow = qbase + sub * 16 + g * 4 + r;
        float inv = 1.f / ldv[r];
#pragma unroll
        for (int n = 0; n < 4; ++n)
          Ob[(size_t)qrow * D + n * 16 + ql] = __float2bfloat16(oacc[sub][n][r] * inv);
      }
    }
  }
}

extern "C" void kernel_launch(void* const* d_in, const int* in_sizes, int n_in,
                              void* d_out, int out_size, void* d_ws, size_t ws_size,
                              hipStream_t stream) {
  const float* x  = (const float*)d_in[0];
  const float* wq = (const float*)d_in[1];
  const float* wk = (const float*)d_in[2];
  const float* wv = (const float*)d_in[3];
  const float* wo = (const float*)d_in[4];

  char* ws = (char*)d_ws;
  bf16* xb  = (bf16*)(ws);                      // 16 MB  [8192,1024]
  bf16* wqb = (bf16*)(ws + (16u << 20));        // 2 MB
  bf16* wkb = (bf16*)(ws + (18u << 20));
  bf16* wvb = (bf16*)(ws + (20u << 20));
  bf16* wob = (bf16*)(ws + (22u << 20));
  bf16* Qb  = (bf16*)(ws + (24u << 20));        // 16 MB [B,H,S,64] (pre-scaled 1/8)
  bf16* Kb  = (bf16*)(ws + (40u << 20));        // 16 MB [B,H,S,64]
  bf16* Vtb = (bf16*)(ws + (56u << 20));        // 16 MB [B,H,64,S]
  bf16* Ob  = (bf16*)(ws + (72u << 20));        // 16 MB [8192,1024]

  cvt_bf16_kernel<<<2048, 256, 0, stream>>>(x, xb, M * D);
  cvt_w4_kernel<<<dim3(256, 4), 256, 0, stream>>>(wq, wk, wv, wo, wqb, wkb, wvb, wob);

  // Q = x Wq^T (scaled 1/8), K = x Wk^T  -> [B,H,S,64]
  gemm_bt<0><<<dim3(M / 128, D / 128), 256, 0, stream>>>(xb, wqb, Qb, D, D, 0.125f);
  gemm_bt<0><<<dim3(M / 128, D / 128), 256, 0, stream>>>(xb, wkb, Kb, D, D, 1.0f);
  // Vt = Wv x^T -> [B,H,64,S]
  gemm_bt<1><<<dim3(D / 128, M / 128), 256, 0, stream>>>(wvb, xb, Vtb, D, D, 1.0f);

  attn_kernel<<<dim3(512), 256, 0, stream>>>(Qb, Kb, Vtb, Ob);

  // out = O Wo^T (fp32)
  gemm_bt<2><<<dim3(M / 128, D / 128), 256, 0, stream>>>(Ob, wob, d_out, D, D, 1.0f);
}